// Round 12
// baseline (172.853 us; speedup 1.0000x reference)
//
#include <hip/hip_runtime.h>
#include <hip/hip_bf16.h>

#define ALPHA 0.9f
#define BETA  0.85f
#define TSIM  50
#define BATCH 128
#define N0    1024
#define N1    2048
#define N2    2048
#define N3    512

// alpha^50, beta^50, 1/(alpha-beta)
#define A50   0.00515379f
#define B50   0.000295764f
#define INVAB 20.0f

typedef __attribute__((ext_vector_type(8))) short bf16x8;
typedef __attribute__((ext_vector_type(4))) float f32x4;

#define GLOBAL_AS __attribute__((address_space(1)))
#define LDS_AS    __attribute__((address_space(3)))

// preprocessor repeat lists (t = literal timestep)
#define R32(X) X(0) X(1) X(2) X(3) X(4) X(5) X(6) X(7) X(8) X(9) X(10) X(11) \
               X(12) X(13) X(14) X(15) X(16) X(17) X(18) X(19) X(20) X(21)   \
               X(22) X(23) X(24) X(25) X(26) X(27) X(28) X(29) X(30) X(31)
#define R18(X) X(32) X(33) X(34) X(35) X(36) X(37) X(38) X(39) X(40) X(41)   \
               X(42) X(43) X(44) X(45) X(46) X(47) X(48) X(49)
#define R50(X) R32(X) R18(X)

#define DECLC(t)   float c##t = 0.f;
#define PROBELO(t) c##t += w * (float)((lo >> (t)) & 1u);
#define PROBEHI(t) c##t += w * (float)((hi >> ((t) - 32)) & 1u);
#define STEPT(t)                                                  \
    s = ALPHA * s + (base + c##t);                                \
    m = BETA * m + s;                                             \
    if (m - 1.f > 0.f) { a2 += (pa - pb) * INVAB; m = 0.f; }      \
    pa *= inva;                                                   \
    pb *= invb;

// ---------------------------------------------------------------------------
// Split-K fp32 tiled GEMM core (device fn): Cp[z] = A(M,Kchunk z)@B(chunk,N).
// ---------------------------------------------------------------------------
__device__ __forceinline__ void gemm_f32_core(const float* __restrict__ A,
                                              const float* __restrict__ B,
                                              float* __restrict__ Cp,
                                              int M, int N, int K, int KC,
                                              int bx, int by, int z,
                                              float As[16][65], float Bs[16][68]) {
    const int tid = threadIdx.x;
    const int tx  = tid % 16;
    const int ty  = tid / 16;

    float acc[4][4] = {};

    const int ar = tid / 4;
    const int ak = (tid % 4) * 4;
    const int br = tid / 16;
    const int bc = (tid % 16) * 4;

    const int kbeg = z * KC;
    for (int k0 = kbeg; k0 < kbeg + KC; k0 += 16) {
        float4 av = *(const float4*)&A[(size_t)(by * 64 + ar) * K + k0 + ak];
        As[ak + 0][ar] = av.x;
        As[ak + 1][ar] = av.y;
        As[ak + 2][ar] = av.z;
        As[ak + 3][ar] = av.w;
        float4 bv = *(const float4*)&B[(size_t)(k0 + br) * N + bx * 64 + bc];
        *(float4*)&Bs[br][bc] = bv;
        __syncthreads();

#pragma unroll
        for (int kk = 0; kk < 16; ++kk) {
            float a0 = As[kk][ty * 4 + 0];
            float a1 = As[kk][ty * 4 + 1];
            float a2 = As[kk][ty * 4 + 2];
            float a3 = As[kk][ty * 4 + 3];
            float b0 = Bs[kk][tx * 4 + 0];
            float b1 = Bs[kk][tx * 4 + 1];
            float b2 = Bs[kk][tx * 4 + 2];
            float b3 = Bs[kk][tx * 4 + 3];
            acc[0][0] += a0 * b0; acc[0][1] += a0 * b1; acc[0][2] += a0 * b2; acc[0][3] += a0 * b3;
            acc[1][0] += a1 * b0; acc[1][1] += a1 * b1; acc[1][2] += a1 * b2; acc[1][3] += a1 * b3;
            acc[2][0] += a2 * b0; acc[2][1] += a2 * b1; acc[2][2] += a2 * b2; acc[2][3] += a2 * b3;
            acc[3][0] += a3 * b0; acc[3][1] += a3 * b1; acc[3][2] += a3 * b2; acc[3][3] += a3 * b3;
        }
        __syncthreads();
    }

#pragma unroll
    for (int i = 0; i < 4; ++i) {
        float4 v = make_float4(acc[i][0], acc[i][1], acc[i][2], acc[i][3]);
        *(float4*)&Cp[((size_t)z * M + by * 64 + ty * 4 + i) * N + bx * 64 + tx * 4] = v;
    }
}

// ---------------------------------------------------------------------------
// Stage-0 fused (block-partitioned; the two workloads are independent):
//   blocks [0, 4096):    W1(K,N) -> transposed bf16 hi/lo pair (N,K)
//   blocks [4096, 4352): P0[z] = inputs @ W0 chunk z (split-K 4)
// Saves one dispatch gap and overlaps ~8us transpose with ~8us GEMM.
// ---------------------------------------------------------------------------
__global__ __launch_bounds__(256) void stage0_fused(const float* __restrict__ W1,
                                                    __hip_bfloat16* __restrict__ Th,
                                                    __hip_bfloat16* __restrict__ Tl,
                                                    const float* __restrict__ inputs,
                                                    const float* __restrict__ W0,
                                                    float* __restrict__ P0) {
    __shared__ float As[16][65];
    __shared__ float Bs[16][68];
    __shared__ float tile[32][33];

    const int bid = blockIdx.x;
    if (bid < 4096) {
        // ---- split-transpose of W1 (N1 x N2) ----
        const int tx = threadIdx.x % 32;
        const int ty = threadIdx.x / 32;
        const int n0 = (bid & 63) * 32;
        const int k0 = (bid >> 6) * 32;

#pragma unroll
        for (int i = 0; i < 4; ++i)
            tile[ty + i * 8][tx] = W1[(size_t)(k0 + ty + i * 8) * N2 + n0 + tx];
        __syncthreads();

#pragma unroll
        for (int i = 0; i < 4; ++i) {
            const float w = tile[tx][ty + i * 8];
            const __hip_bfloat16 hi = __float2bfloat16(w);
            const float lo = w - __bfloat162float(hi);
            const size_t o = (size_t)(n0 + ty + i * 8) * N1 + k0 + tx;
            Th[o] = hi;
            Tl[o] = __float2bfloat16(lo);
        }
    } else {
        // ---- gemm1: P0[z] = inputs @ W0 chunk z  (grid 32 x 2 x 4) ----
        const int g  = bid - 4096;
        const int bx = g & 31;
        const int by = (g >> 5) & 1;
        const int z  = g >> 6;
        gemm_f32_core(inputs, W0, P0, BATCH, N1, N0, N0 / 4, bx, by, z, As, Bs);
    }
}

// ---------------------------------------------------------------------------
// Plain split-K fp32 GEMM kernel (A2 @ W2, split-K 16).
// Partials + consumer reduce (round 6: atomic reduction = 2x cost).
// ---------------------------------------------------------------------------
__global__ __launch_bounds__(256) void gemm_f32_splitk(const float* __restrict__ A,
                                                       const float* __restrict__ B,
                                                       float* __restrict__ Cp,
                                                       int M, int N, int K, int KC) {
    __shared__ float As[16][65];
    __shared__ float Bs[16][68];
    gemm_f32_core(A, B, Cp, M, N, K, KC, blockIdx.x, blockIdx.y, blockIdx.z, As, Bs);
}

// ---------------------------------------------------------------------------
// Split-K MFMA GEMM: Cp[z] = A(M,Kchunk) @ (Bh+Bl)^T. A bf16 (exact {0,1}),
// Bh/Bl (N,K) bf16 hi/lo, fp32 accumulate. BM=128, BK=32.
// ---------------------------------------------------------------------------
template <int BN, int WGM, int WGN, int WMT, int WNT>
__global__ __launch_bounds__(256) void gemm_bf16_split_k(const __hip_bfloat16* __restrict__ A,
                                                         const __hip_bfloat16* __restrict__ Bh,
                                                         const __hip_bfloat16* __restrict__ Bl,
                                                         float* __restrict__ Cp,
                                                         int M, int N, int K, int KC) {
    constexpr int BM = 128;
    constexpr int BK = 32;
    constexpr int NA = (BM * BK) / (256 * 8);
    constexpr int NB = (BN * BK) / (256 * 8);

    __shared__ alignas(16) __hip_bfloat16 As[BM * BK];
    __shared__ alignas(16) __hip_bfloat16 Bhs[BN * BK];
    __shared__ alignas(16) __hip_bfloat16 Bls[BN * BK];

    const int tid  = threadIdx.x;
    const int wave = tid >> 6;
    const int lane = tid & 63;
    const int quad = lane >> 4;
    const int l16  = lane & 15;

    const int m0 = blockIdx.y * BM;
    const int n0 = blockIdx.x * BN;
    const int z  = blockIdx.z;

    const int wm = (wave % WGM) * (WMT * 16);
    const int wn = (wave / WGM) * (WNT * 16);

    f32x4 acc[WMT][WNT] = {};

    const __hip_bfloat16* agp[NA];
    int aoff[NA];
#pragma unroll
    for (int i = 0; i < NA; ++i) {
        const int c = i * 256 + tid;
        agp[i]  = A + (size_t)(m0 + (c >> 2)) * K + (c & 3) * 8;
        aoff[i] = c * 8;
    }
    const __hip_bfloat16 *bhgp[NB], *blgp[NB];
    int boff[NB];
#pragma unroll
    for (int i = 0; i < NB; ++i) {
        const int c = i * 256 + tid;
        bhgp[i] = Bh + (size_t)(n0 + (c >> 2)) * K + (c & 3) * 8;
        blgp[i] = Bl + (size_t)(n0 + (c >> 2)) * K + (c & 3) * 8;
        boff[i] = c * 8;
    }

    const int kbeg = z * KC;
    for (int k0 = kbeg; k0 < kbeg + KC; k0 += BK) {
#pragma unroll
        for (int i = 0; i < NA; ++i)
            __builtin_amdgcn_global_load_lds((const GLOBAL_AS void*)(agp[i] + k0),
                                             (LDS_AS void*)&As[aoff[i]], 16, 0, 0);
#pragma unroll
        for (int i = 0; i < NB; ++i) {
            __builtin_amdgcn_global_load_lds((const GLOBAL_AS void*)(bhgp[i] + k0),
                                             (LDS_AS void*)&Bhs[boff[i]], 16, 0, 0);
            __builtin_amdgcn_global_load_lds((const GLOBAL_AS void*)(blgp[i] + k0),
                                             (LDS_AS void*)&Bls[boff[i]], 16, 0, 0);
        }
        __syncthreads();

        bf16x8 af[WMT], bhf[WNT], blf[WNT];
#pragma unroll
        for (int i = 0; i < WMT; ++i)
            af[i] = *(const bf16x8*)&As[(wm + i * 16 + l16) * BK + quad * 8];
#pragma unroll
        for (int j = 0; j < WNT; ++j) {
            bhf[j] = *(const bf16x8*)&Bhs[(wn + j * 16 + l16) * BK + quad * 8];
            blf[j] = *(const bf16x8*)&Bls[(wn + j * 16 + l16) * BK + quad * 8];
        }
#pragma unroll
        for (int i = 0; i < WMT; ++i)
#pragma unroll
            for (int j = 0; j < WNT; ++j) {
                acc[i][j] = __builtin_amdgcn_mfma_f32_16x16x32_bf16(af[i], bhf[j], acc[i][j], 0, 0, 0);
                acc[i][j] = __builtin_amdgcn_mfma_f32_16x16x32_bf16(af[i], blf[j], acc[i][j], 0, 0, 0);
            }
        __syncthreads();
    }

    // C/D layout: col = lane&15, row = quad*4 + reg
#pragma unroll
    for (int i = 0; i < WMT; ++i)
#pragma unroll
        for (int j = 0; j < WNT; ++j)
#pragma unroll
            for (int r = 0; r < 4; ++r)
                Cp[((size_t)z * M + m0 + wm + i * 16 + quad * 4 + r) * N + n0 + wn + j * 16 + l16] =
                    acc[i][j][r];
}

// ---------------------------------------------------------------------------
// Layer-0 simulate + classify (deterministic per-(b,chunk) residual lists).
// Sums 4 split-K partials (gemm1 now split-K 4).
// ---------------------------------------------------------------------------
__global__ __launch_bounds__(256) void scan_l0_classify(const float* __restrict__ P0,
                                                        __hip_bfloat16* __restrict__ C0,
                                                        int* __restrict__ jlist0,
                                                        unsigned long long* __restrict__ mask0,
                                                        int* __restrict__ count0) {
    const int b     = blockIdx.x;
    const int chunk = blockIdx.y;
    const int tid   = threadIdx.x;
    const int j     = chunk * 256 + tid;
    const int lane  = tid & 63;
    const int wv    = tid >> 6;

    float h = 0.f;
#pragma unroll
    for (int z = 0; z < 4; ++z) h += P0[((size_t)z * BATCH + b) * N1 + j];

    float m = 0.f;
    unsigned long long mask = 0ull;
#pragma unroll
    for (int t = 0; t < TSIM; ++t) {
        m = BETA * m + h;
        if (m - 1.f > 0.f) { mask |= (1ull << t); m = 0.f; }
    }
    const unsigned long long FULL = (1ull << TSIM) - 1ull;
    C0[(size_t)b * N1 + j] = __float2bfloat16((mask == FULL) ? 1.f : 0.f);

    const bool has = (mask != 0ull) && (mask != FULL);
    const unsigned long long bal = __ballot(has);

    __shared__ int wcnt[4];
    if (lane == 0) wcnt[wv] = __popcll(bal);
    __syncthreads();
    int base = 0;
#pragma unroll
    for (int w = 0; w < 4; ++w)
        if (w < wv) base += wcnt[w];
    const int pos = base + __popcll(bal & ((1ull << lane) - 1ull));

    const size_t lbase = (size_t)(b * 8 + chunk) * 256;
    if (has) {
        jlist0[lbase + pos] = j;
        mask0[lbase + pos]  = mask;
    }
    if (tid == 0) count0[b * 8 + chunk] = wcnt[0] + wcnt[1] + wcnt[2] + wcnt[3];
}

// ---------------------------------------------------------------------------
// Layer-1 fused drive + membrane scan + linear layer-2 projection.
// 50 named scalar accumulators + __launch_bounds__(256,2): the (256,2)
// register budget (~256 VGPR) is what finally stopped the allocator from
// spilling the accumulators (rounds 4-10: VGPR_Count 36-68, h1 35-79us;
// round 11: h1 out of top-5). Do not lower the bound.
// ---------------------------------------------------------------------------
__global__ __launch_bounds__(256, 2) void h1_scan_a2(const float* __restrict__ PB1,
                                                     const float* __restrict__ W1,
                                                     const int* __restrict__ jlist0,
                                                     const unsigned long long* __restrict__ mask0,
                                                     const int* __restrict__ count0,
                                                     float* __restrict__ A2) {
    const int b  = blockIdx.x;
    const int jc = blockIdx.y * 256 + threadIdx.x;

    float base = 0.f;
#pragma unroll
    for (int z = 0; z < 16; ++z) base += PB1[((size_t)z * BATCH + b) * N2 + jc];

    R50(DECLC)

    for (int c = 0; c < 8; ++c) {
        const int cnt      = count0[b * 8 + c];
        const size_t lbase = (size_t)(b * 8 + c) * 256;
        for (int e = 0; e < cnt; ++e) {
            const unsigned long long mk = mask0[lbase + e];
            const int j                 = jlist0[lbase + e];
            const float w               = W1[(size_t)j * N2 + jc];
            const unsigned lo = (unsigned)mk, hi = (unsigned)(mk >> 32);
            R32(PROBELO)
            R18(PROBEHI)
        }
    }

    // membrane scan with folded linear output-layer weight w_t
    float s = 0.f, m = 0.f, a2 = 0.f;
    float pa = A50, pb = B50;
    const float inva = 1.0f / ALPHA, invb = 1.0f / BETA;
    R50(STEPT)

    A2[(size_t)b * N2 + jc] = a2;
}

// ---------------------------------------------------------------------------
// Sum 16 split-K partials of A2@W2 -> final output (128 x 512).
// ---------------------------------------------------------------------------
__global__ __launch_bounds__(256) void reduce_out(const float* __restrict__ PB2,
                                                  float* __restrict__ out) {
    const int idx = blockIdx.x * 256 + threadIdx.x;
    float v = 0.f;
#pragma unroll
    for (int z = 0; z < 16; ++z) v += PB2[(size_t)z * (BATCH * N3) + idx];
    out[idx] = v;
}

extern "C" void kernel_launch(void* const* d_in, const int* in_sizes, int n_in,
                              void* d_out, int out_size, void* d_ws, size_t ws_size,
                              hipStream_t stream) {
    const float* inputs = (const float*)d_in[0];   // (128, 1024)
    const float* W0     = (const float*)d_in[1];   // (1024, 2048)
    const float* W1     = (const float*)d_in[2];   // (2048, 2048)
    const float* W2     = (const float*)d_in[3];   // (2048, 512)
    float* out = (float*)d_out;                    // (128, 512)

    // workspace layout (~48 MB)
    float* P0  = (float*)d_ws;                         // 4 x 128 x 2048   fp32
    float* PB1 = P0 + 4 * BATCH * N1;                  // 16 x 128 x 2048  fp32
    float* A2  = PB1 + 16 * BATCH * N2;                // 128 x 2048       fp32
    float* PB2 = A2 + BATCH * N2;                      // 16 x 128 x 512   fp32
    unsigned long long* mk0 = (unsigned long long*)(PB2 + 16 * BATCH * N3);  // 128x8x256
    __hip_bfloat16* C0bf = (__hip_bfloat16*)(mk0 + BATCH * 8 * 256);         // 128 x 2048
    __hip_bfloat16* W1th = C0bf + (size_t)BATCH * N1;                        // 2048 x 2048
    __hip_bfloat16* W1tl = W1th + (size_t)N2 * N1;                           // 2048 x 2048
    int* jl0  = (int*)(W1tl + (size_t)N2 * N1);                              // 128 x 8 x 256
    int* cnt0 = jl0 + BATCH * 8 * 256;                                       // 128 x 8

    // 1. fused: W1 split-transpose (4096 blocks) + inputs@W0 split-K 4 (256)
    stage0_fused<<<4096 + 256, 256, 0, stream>>>(W1, W1th, W1tl, inputs, W0, P0);

    // 2. layer-0 simulate + classify -> C0 (bf16), residual lists
    scan_l0_classify<<<dim3(BATCH, N1 / 256), 256, 0, stream>>>(P0, C0bf, jl0, mk0, cnt0);

    // 3. PB1[z] = C0 @ W1 chunks      (128 x 2048 x 2048, split-K 16, MFMA hi+lo)
    gemm_bf16_split_k<128, 2, 2, 4, 4>
        <<<dim3(N2 / 128, BATCH / 128, 16), 256, 0, stream>>>(
            C0bf, W1th, W1tl, PB1, BATCH, N2, N1, N1 / 16);

    // 4. fused layer-1 drive + scan + linear layer-2 projection -> A2
    h1_scan_a2<<<dim3(BATCH, N2 / 256), 256, 0, stream>>>(
        PB1, W1, jl0, mk0, cnt0, A2);

    // 5. PB2[z] = A2 @ W2 chunks      (128 x 2048 x 512, split-K 16, fp32)
    gemm_f32_splitk<<<dim3(N3 / 64, BATCH / 64, 16), 256, 0, stream>>>(
        A2, W2, PB2, BATCH, N3, N2, N2 / 16);

    // 6. sum partials -> final membrane (128 x 512)
    reduce_out<<<(BATCH * N3) / 256, 256, 0, stream>>>(PB2, out);
}

// Round 14
// 148.990 us; speedup vs baseline: 1.1602x; 1.1602x over previous
//
#include <hip/hip_runtime.h>
#include <hip/hip_bf16.h>

#define ALPHA 0.9f
#define BETA  0.85f
#define TSIM  50
#define BATCH 128
#define N0    1024
#define N1    2048
#define N2    2048
#define N3    512

// alpha^50, beta^50, 1/(alpha-beta)
#define A50   0.00515379f
#define B50   0.000295764f
#define INVAB 20.0f

typedef __attribute__((ext_vector_type(8))) short bf16x8;
typedef __attribute__((ext_vector_type(8))) unsigned short ushort8;
typedef __attribute__((ext_vector_type(4))) float f32x4;

#define GLOBAL_AS __attribute__((address_space(1)))
#define LDS_AS    __attribute__((address_space(3)))

// preprocessor repeat lists (t = literal timestep)
#define R32(X) X(0) X(1) X(2) X(3) X(4) X(5) X(6) X(7) X(8) X(9) X(10) X(11) \
               X(12) X(13) X(14) X(15) X(16) X(17) X(18) X(19) X(20) X(21)   \
               X(22) X(23) X(24) X(25) X(26) X(27) X(28) X(29) X(30) X(31)
#define R18(X) X(32) X(33) X(34) X(35) X(36) X(37) X(38) X(39) X(40) X(41)   \
               X(42) X(43) X(44) X(45) X(46) X(47) X(48) X(49)
#define R50(X) R32(X) R18(X)

#define DECLC(t)   float c##t = 0.f;
#define PROBELO(t) c##t += w * (float)((lo >> (t)) & 1u);
#define PROBEHI(t) c##t += w * (float)((hi >> ((t) - 32)) & 1u);
#define STEPT(t)                                                  \
    s = ALPHA * s + (base + c##t);                                \
    m = BETA * m + s;                                             \
    if (m - 1.f > 0.f) { a2 += (pa - pb) * INVAB; m = 0.f; }      \
    pa *= inva;                                                   \
    pb *= invb;

// ---------------------------------------------------------------------------
// Split-K fp32 tiled GEMM: Cp[z] = A(M, K-chunk z) @ B(chunk z, N).
// Partials + consumer-side reduction (round 6: atomicAdd reduction = 2x cost).
// ---------------------------------------------------------------------------
__global__ __launch_bounds__(256) void gemm_f32_splitk(const float* __restrict__ A,
                                                       const float* __restrict__ B,
                                                       float* __restrict__ Cp,
                                                       int M, int N, int K, int KC) {
    __shared__ float As[16][65];
    __shared__ float Bs[16][68];

    const int tid = threadIdx.x;
    const int tx  = tid % 16;
    const int ty  = tid / 16;
    const int bx  = blockIdx.x;
    const int by  = blockIdx.y;
    const int z   = blockIdx.z;

    float acc[4][4] = {};

    const int ar = tid / 4;
    const int ak = (tid % 4) * 4;
    const int br = tid / 16;
    const int bc = (tid % 16) * 4;

    const int kbeg = z * KC;
    for (int k0 = kbeg; k0 < kbeg + KC; k0 += 16) {
        float4 av = *(const float4*)&A[(size_t)(by * 64 + ar) * K + k0 + ak];
        As[ak + 0][ar] = av.x;
        As[ak + 1][ar] = av.y;
        As[ak + 2][ar] = av.z;
        As[ak + 3][ar] = av.w;
        float4 bv = *(const float4*)&B[(size_t)(k0 + br) * N + bx * 64 + bc];
        *(float4*)&Bs[br][bc] = bv;
        __syncthreads();

#pragma unroll
        for (int kk = 0; kk < 16; ++kk) {
            float a0 = As[kk][ty * 4 + 0];
            float a1 = As[kk][ty * 4 + 1];
            float a2 = As[kk][ty * 4 + 2];
            float a3 = As[kk][ty * 4 + 3];
            float b0 = Bs[kk][tx * 4 + 0];
            float b1 = Bs[kk][tx * 4 + 1];
            float b2 = Bs[kk][tx * 4 + 2];
            float b3 = Bs[kk][tx * 4 + 3];
            acc[0][0] += a0 * b0; acc[0][1] += a0 * b1; acc[0][2] += a0 * b2; acc[0][3] += a0 * b3;
            acc[1][0] += a1 * b0; acc[1][1] += a1 * b1; acc[1][2] += a1 * b2; acc[1][3] += a1 * b3;
            acc[2][0] += a2 * b0; acc[2][1] += a2 * b1; acc[2][2] += a2 * b2; acc[2][3] += a2 * b3;
            acc[3][0] += a3 * b0; acc[3][1] += a3 * b1; acc[3][2] += a3 * b2; acc[3][3] += a3 * b3;
        }
        __syncthreads();
    }

#pragma unroll
    for (int i = 0; i < 4; ++i) {
        float4 v = make_float4(acc[i][0], acc[i][1], acc[i][2], acc[i][3]);
        *(float4*)&Cp[((size_t)z * M + by * 64 + ty * 4 + i) * N + bx * 64 + tx * 4] = v;
    }
}

// ---------------------------------------------------------------------------
// FAST split-transpose: W(K=2048, N=2048) fp32 -> Th,Tl (N,K) bf16.
// Tile 128(k) x 32(n), staged fp32 in LDS (coalesced reads). Emit: thread
// (nl = tid/8, oct = tid%8) writes TWO k-octets (half*64 + oct*8) — 16
// elements/thread x 256 = 4096 = full tile (round 13 bug: wrote only half).
// LDS read bank = (8*oct + nl + c) % 32: 8*oct+nl covers 0..63 uniquely ->
// every bank exactly 2x/wave = free (m136). Stores: lanes 0..7 fill one
// 128B line per n-row -> all lines fully utilized (old kernel: 2B scalar
// stores, ~40-50us; this: ~50MB at >3TB/s ≈ 12us).
// ---------------------------------------------------------------------------
__global__ __launch_bounds__(256) void split_transpose_fast(const float* __restrict__ W,
                                                            __hip_bfloat16* __restrict__ Th,
                                                            __hip_bfloat16* __restrict__ Tl) {
    __shared__ float Wf[128][33];

    const int tid = threadIdx.x;
    const int n0  = blockIdx.x * 32;    // 64 n-tiles
    const int k0  = blockIdx.y * 128;   // 16 k-tiles

    // stage: 128x32 fp32 tile, consecutive lanes -> consecutive n (coalesced)
#pragma unroll
    for (int it = 0; it < 16; ++it) {
        const int idx = it * 256 + tid;
        const int kk  = idx >> 5;          // 0..127
        const int nn  = idx & 31;          // 0..31
        Wf[kk][nn] = W[(size_t)(k0 + kk) * N2 + n0 + nn];
    }
    __syncthreads();

    // emit: thread owns n = tid/8 and TWO k-octets: oct*8 and 64 + oct*8
    const int nl  = tid >> 3;              // 0..31
    const int oct = tid & 7;               // 0..7

#pragma unroll
    for (int half = 0; half < 2; ++half) {
        const int kb = half * 64 + oct * 8;
        ushort8 vh, vl;
#pragma unroll
        for (int u = 0; u < 8; ++u) {
            const float w = Wf[kb + u][nl];
            const __hip_bfloat16 hi = __float2bfloat16(w);
            const float lo = w - __bfloat162float(hi);
            const __hip_bfloat16 lb = __float2bfloat16(lo);
            vh[u] = *(const unsigned short*)&hi;
            vl[u] = *(const unsigned short*)&lb;
        }
        const size_t o = (size_t)(n0 + nl) * N1 + k0 + kb;
        *(ushort8*)&Th[o] = vh;
        *(ushort8*)&Tl[o] = vl;
    }
}

// ---------------------------------------------------------------------------
// Split-K MFMA GEMM: Cp[z] = A(M,Kchunk) @ (Bh+Bl)^T. A bf16 (exact {0,1}),
// Bh/Bl (N,K) bf16 hi/lo, fp32 accumulate. BM=128, BK=32.
// ---------------------------------------------------------------------------
template <int BN, int WGM, int WGN, int WMT, int WNT>
__global__ __launch_bounds__(256) void gemm_bf16_split_k(const __hip_bfloat16* __restrict__ A,
                                                         const __hip_bfloat16* __restrict__ Bh,
                                                         const __hip_bfloat16* __restrict__ Bl,
                                                         float* __restrict__ Cp,
                                                         int M, int N, int K, int KC) {
    constexpr int BM = 128;
    constexpr int BK = 32;
    constexpr int NA = (BM * BK) / (256 * 8);
    constexpr int NB = (BN * BK) / (256 * 8);

    __shared__ alignas(16) __hip_bfloat16 As[BM * BK];
    __shared__ alignas(16) __hip_bfloat16 Bhs[BN * BK];
    __shared__ alignas(16) __hip_bfloat16 Bls[BN * BK];

    const int tid  = threadIdx.x;
    const int wave = tid >> 6;
    const int lane = tid & 63;
    const int quad = lane >> 4;
    const int l16  = lane & 15;

    const int m0 = blockIdx.y * BM;
    const int n0 = blockIdx.x * BN;
    const int z  = blockIdx.z;

    const int wm = (wave % WGM) * (WMT * 16);
    const int wn = (wave / WGM) * (WNT * 16);

    f32x4 acc[WMT][WNT] = {};

    const __hip_bfloat16* agp[NA];
    int aoff[NA];
#pragma unroll
    for (int i = 0; i < NA; ++i) {
        const int c = i * 256 + tid;
        agp[i]  = A + (size_t)(m0 + (c >> 2)) * K + (c & 3) * 8;
        aoff[i] = c * 8;
    }
    const __hip_bfloat16 *bhgp[NB], *blgp[NB];
    int boff[NB];
#pragma unroll
    for (int i = 0; i < NB; ++i) {
        const int c = i * 256 + tid;
        bhgp[i] = Bh + (size_t)(n0 + (c >> 2)) * K + (c & 3) * 8;
        blgp[i] = Bl + (size_t)(n0 + (c >> 2)) * K + (c & 3) * 8;
        boff[i] = c * 8;
    }

    const int kbeg = z * KC;
    for (int k0 = kbeg; k0 < kbeg + KC; k0 += BK) {
#pragma unroll
        for (int i = 0; i < NA; ++i)
            __builtin_amdgcn_global_load_lds((const GLOBAL_AS void*)(agp[i] + k0),
                                             (LDS_AS void*)&As[aoff[i]], 16, 0, 0);
#pragma unroll
        for (int i = 0; i < NB; ++i) {
            __builtin_amdgcn_global_load_lds((const GLOBAL_AS void*)(bhgp[i] + k0),
                                             (LDS_AS void*)&Bhs[boff[i]], 16, 0, 0);
            __builtin_amdgcn_global_load_lds((const GLOBAL_AS void*)(blgp[i] + k0),
                                             (LDS_AS void*)&Bls[boff[i]], 16, 0, 0);
        }
        __syncthreads();

        bf16x8 af[WMT], bhf[WNT], blf[WNT];
#pragma unroll
        for (int i = 0; i < WMT; ++i)
            af[i] = *(const bf16x8*)&As[(wm + i * 16 + l16) * BK + quad * 8];
#pragma unroll
        for (int j = 0; j < WNT; ++j) {
            bhf[j] = *(const bf16x8*)&Bhs[(wn + j * 16 + l16) * BK + quad * 8];
            blf[j] = *(const bf16x8*)&Bls[(wn + j * 16 + l16) * BK + quad * 8];
        }
#pragma unroll
        for (int i = 0; i < WMT; ++i)
#pragma unroll
            for (int j = 0; j < WNT; ++j) {
                acc[i][j] = __builtin_amdgcn_mfma_f32_16x16x32_bf16(af[i], bhf[j], acc[i][j], 0, 0, 0);
                acc[i][j] = __builtin_amdgcn_mfma_f32_16x16x32_bf16(af[i], blf[j], acc[i][j], 0, 0, 0);
            }
        __syncthreads();
    }

    // C/D layout: col = lane&15, row = quad*4 + reg
#pragma unroll
    for (int i = 0; i < WMT; ++i)
#pragma unroll
        for (int j = 0; j < WNT; ++j)
#pragma unroll
            for (int r = 0; r < 4; ++r)
                Cp[((size_t)z * M + m0 + wm + i * 16 + quad * 4 + r) * N + n0 + wn + j * 16 + l16] =
                    acc[i][j][r];
}

// ---------------------------------------------------------------------------
// Layer-0 simulate + classify (deterministic per-(b,chunk) residual lists).
// ---------------------------------------------------------------------------
__global__ __launch_bounds__(256) void scan_l0_classify(const float* __restrict__ P0,
                                                        __hip_bfloat16* __restrict__ C0,
                                                        int* __restrict__ jlist0,
                                                        unsigned long long* __restrict__ mask0,
                                                        int* __restrict__ count0) {
    const int b     = blockIdx.x;
    const int chunk = blockIdx.y;
    const int tid   = threadIdx.x;
    const int j     = chunk * 256 + tid;
    const int lane  = tid & 63;
    const int wv    = tid >> 6;

    float h = 0.f;
#pragma unroll
    for (int z = 0; z < 8; ++z) h += P0[((size_t)z * BATCH + b) * N1 + j];

    float m = 0.f;
    unsigned long long mask = 0ull;
#pragma unroll
    for (int t = 0; t < TSIM; ++t) {
        m = BETA * m + h;
        if (m - 1.f > 0.f) { mask |= (1ull << t); m = 0.f; }
    }
    const unsigned long long FULL = (1ull << TSIM) - 1ull;
    C0[(size_t)b * N1 + j] = __float2bfloat16((mask == FULL) ? 1.f : 0.f);

    const bool has = (mask != 0ull) && (mask != FULL);
    const unsigned long long bal = __ballot(has);

    __shared__ int wcnt[4];
    if (lane == 0) wcnt[wv] = __popcll(bal);
    __syncthreads();
    int base = 0;
#pragma unroll
    for (int w = 0; w < 4; ++w)
        if (w < wv) base += wcnt[w];
    const int pos = base + __popcll(bal & ((1ull << lane) - 1ull));

    const size_t lbase = (size_t)(b * 8 + chunk) * 256;
    if (has) {
        jlist0[lbase + pos] = j;
        mask0[lbase + pos]  = mask;
    }
    if (tid == 0) count0[b * 8 + chunk] = wcnt[0] + wcnt[1] + wcnt[2] + wcnt[3];
}

// ---------------------------------------------------------------------------
// Layer-1 fused drive + membrane scan + linear layer-2 projection.
// 50 named scalar accumulators + __launch_bounds__(256,2): the (256,2)
// register budget (~256 VGPR) is what stopped the allocator from spilling
// (rounds 4-10: VGPR_Count 36-68, h1 35-79us; round 11: out of top-5).
// Do not lower the bound.
// ---------------------------------------------------------------------------
__global__ __launch_bounds__(256, 2) void h1_scan_a2(const float* __restrict__ PB1,
                                                     const float* __restrict__ W1,
                                                     const int* __restrict__ jlist0,
                                                     const unsigned long long* __restrict__ mask0,
                                                     const int* __restrict__ count0,
                                                     float* __restrict__ A2) {
    const int b  = blockIdx.x;
    const int jc = blockIdx.y * 256 + threadIdx.x;

    float base = 0.f;
#pragma unroll
    for (int z = 0; z < 16; ++z) base += PB1[((size_t)z * BATCH + b) * N2 + jc];

    R50(DECLC)

    for (int c = 0; c < 8; ++c) {
        const int cnt      = count0[b * 8 + c];
        const size_t lbase = (size_t)(b * 8 + c) * 256;
        for (int e = 0; e < cnt; ++e) {
            const unsigned long long mk = mask0[lbase + e];
            const int j                 = jlist0[lbase + e];
            const float w               = W1[(size_t)j * N2 + jc];
            const unsigned lo = (unsigned)mk, hi = (unsigned)(mk >> 32);
            R32(PROBELO)
            R18(PROBEHI)
        }
    }

    // membrane scan with folded linear output-layer weight w_t
    float s = 0.f, m = 0.f, a2 = 0.f;
    float pa = A50, pb = B50;
    const float inva = 1.0f / ALPHA, invb = 1.0f / BETA;
    R50(STEPT)

    A2[(size_t)b * N2 + jc] = a2;
}

// ---------------------------------------------------------------------------
// Sum 16 split-K partials of A2@W2 -> final output (128 x 512).
// ---------------------------------------------------------------------------
__global__ __launch_bounds__(256) void reduce_out(const float* __restrict__ PB2,
                                                  float* __restrict__ out) {
    const int idx = blockIdx.x * 256 + threadIdx.x;
    float v = 0.f;
#pragma unroll
    for (int z = 0; z < 16; ++z) v += PB2[(size_t)z * (BATCH * N3) + idx];
    out[idx] = v;
}

extern "C" void kernel_launch(void* const* d_in, const int* in_sizes, int n_in,
                              void* d_out, int out_size, void* d_ws, size_t ws_size,
                              hipStream_t stream) {
    const float* inputs = (const float*)d_in[0];   // (128, 1024)
    const float* W0     = (const float*)d_in[1];   // (1024, 2048)
    const float* W1     = (const float*)d_in[2];   // (2048, 2048)
    const float* W2     = (const float*)d_in[3];   // (2048, 512)
    float* out = (float*)d_out;                    // (128, 512)

    // workspace layout (~51 MB)  — round-11 structure verbatim
    float* P0  = (float*)d_ws;                         // 8 x 128 x 2048   fp32
    float* PB1 = P0 + 8 * BATCH * N1;                  // 16 x 128 x 2048  fp32
    float* A2  = PB1 + 16 * BATCH * N2;                // 128 x 2048       fp32
    float* PB2 = A2 + BATCH * N2;                      // 16 x 128 x 512   fp32
    unsigned long long* mk0 = (unsigned long long*)(PB2 + 16 * BATCH * N3);  // 128x8x256
    __hip_bfloat16* C0bf = (__hip_bfloat16*)(mk0 + BATCH * 8 * 256);         // 128 x 2048
    __hip_bfloat16* W1th = C0bf + (size_t)BATCH * N1;                        // 2048 x 2048
    __hip_bfloat16* W1tl = W1th + (size_t)N2 * N1;                           // 2048 x 2048
    int* jl0  = (int*)(W1tl + (size_t)N2 * N1);                              // 128 x 8 x 256
    int* cnt0 = jl0 + BATCH * 8 * 256;                                       // 128 x 8

    // 0. W1 -> transposed bf16 hi/lo pair (fast coalesced transpose)
    split_transpose_fast<<<dim3(N2 / 32, N1 / 128), 256, 0, stream>>>(W1, W1th, W1tl);

    // 1. P0[z] = inputs @ W0 chunks   (128 x 1024 x 2048, split-K 8, fp32)
    gemm_f32_splitk<<<dim3(N1 / 64, BATCH / 64, 8), 256, 0, stream>>>(
        inputs, W0, P0, BATCH, N1, N0, N0 / 8);

    // 2. layer-0 simulate + classify -> C0 (bf16), residual lists
    scan_l0_classify<<<dim3(BATCH, N1 / 256), 256, 0, stream>>>(P0, C0bf, jl0, mk0, cnt0);

    // 3. PB1[z] = C0 @ W1 chunks      (128 x 2048 x 2048, split-K 16, MFMA hi+lo)
    gemm_bf16_split_k<128, 2, 2, 4, 4>
        <<<dim3(N2 / 128, BATCH / 128, 16), 256, 0, stream>>>(
            C0bf, W1th, W1tl, PB1, BATCH, N2, N1, N1 / 16);

    // 4. fused layer-1 drive + scan + linear layer-2 projection -> A2
    h1_scan_a2<<<dim3(BATCH, N2 / 256), 256, 0, stream>>>(
        PB1, W1, jl0, mk0, cnt0, A2);

    // 5. PB2[z] = A2 @ W2 chunks      (128 x 2048 x 512, split-K 16, fp32)
    gemm_f32_splitk<<<dim3(N3 / 64, BATCH / 64, 16), 256, 0, stream>>>(
        A2, W2, PB2, BATCH, N3, N2, N2 / 16);

    // 6. sum partials -> final membrane (128 x 512)
    reduce_out<<<(BATCH * N3) / 256, 256, 0, stream>>>(PB2, out);
}

// Round 15
// 146.955 us; speedup vs baseline: 1.1762x; 1.0138x over previous
//
#include <hip/hip_runtime.h>
#include <hip/hip_bf16.h>
#include <hip/hip_cooperative_groups.h>

namespace cg = cooperative_groups;

#define ALPHA 0.9f
#define BETA  0.85f
#define TSIM  50
#define BATCH 128
#define N0    1024
#define N1    2048
#define N2    2048
#define N3    512

// alpha^50, beta^50, 1/(alpha-beta)
#define A50   0.00515379f
#define B50   0.000295764f
#define INVAB 20.0f

typedef __attribute__((ext_vector_type(8))) short bf16x8;
typedef __attribute__((ext_vector_type(8))) unsigned short ushort8;
typedef __attribute__((ext_vector_type(4))) float f32x4;

#define GLOBAL_AS __attribute__((address_space(1)))
#define LDS_AS    __attribute__((address_space(3)))

// preprocessor repeat lists (t = literal timestep)
#define R32(X) X(0) X(1) X(2) X(3) X(4) X(5) X(6) X(7) X(8) X(9) X(10) X(11) \
               X(12) X(13) X(14) X(15) X(16) X(17) X(18) X(19) X(20) X(21)   \
               X(22) X(23) X(24) X(25) X(26) X(27) X(28) X(29) X(30) X(31)
#define R18(X) X(32) X(33) X(34) X(35) X(36) X(37) X(38) X(39) X(40) X(41)   \
               X(42) X(43) X(44) X(45) X(46) X(47) X(48) X(49)
#define R50(X) R32(X) R18(X)

#define DECLC(t)   float c##t = 0.f;
#define PROBELO(t) c##t += w * (float)((lo >> (t)) & 1u);
#define PROBEHI(t) c##t += w * (float)((hi >> ((t) - 32)) & 1u);
#define STEPT(t)                                                  \
    s = ALPHA * s + (base + c##t);                                \
    m = BETA * m + s;                                             \
    if (m - 1.f > 0.f) { a2 += (pa - pb) * INVAB; m = 0.f; }      \
    pa *= inva;                                                   \
    pb *= invb;

// ---------------------------------------------------------------------------
// Split-K fp32 tiled GEMM core: Cp[z] = A(M, K-chunk z) @ B(chunk z, N).
// ---------------------------------------------------------------------------
__device__ __forceinline__ void gemm_f32_core(const float* __restrict__ A,
                                              const float* __restrict__ B,
                                              float* __restrict__ Cp,
                                              int M, int N, int K, int KC,
                                              int bx, int by, int z,
                                              float As[16][65], float Bs[16][68]) {
    const int tid = threadIdx.x;
    const int tx  = tid % 16;
    const int ty  = tid / 16;

    float acc[4][4] = {};

    const int ar = tid / 4;
    const int ak = (tid % 4) * 4;
    const int br = tid / 16;
    const int bc = (tid % 16) * 4;

    const int kbeg = z * KC;
    for (int k0 = kbeg; k0 < kbeg + KC; k0 += 16) {
        float4 av = *(const float4*)&A[(size_t)(by * 64 + ar) * K + k0 + ak];
        As[ak + 0][ar] = av.x;
        As[ak + 1][ar] = av.y;
        As[ak + 2][ar] = av.z;
        As[ak + 3][ar] = av.w;
        float4 bv = *(const float4*)&B[(size_t)(k0 + br) * N + bx * 64 + bc];
        *(float4*)&Bs[br][bc] = bv;
        __syncthreads();

#pragma unroll
        for (int kk = 0; kk < 16; ++kk) {
            float a0 = As[kk][ty * 4 + 0];
            float a1 = As[kk][ty * 4 + 1];
            float a2 = As[kk][ty * 4 + 2];
            float a3 = As[kk][ty * 4 + 3];
            float b0 = Bs[kk][tx * 4 + 0];
            float b1 = Bs[kk][tx * 4 + 1];
            float b2 = Bs[kk][tx * 4 + 2];
            float b3 = Bs[kk][tx * 4 + 3];
            acc[0][0] += a0 * b0; acc[0][1] += a0 * b1; acc[0][2] += a0 * b2; acc[0][3] += a0 * b3;
            acc[1][0] += a1 * b0; acc[1][1] += a1 * b1; acc[1][2] += a1 * b2; acc[1][3] += a1 * b3;
            acc[2][0] += a2 * b0; acc[2][1] += a2 * b1; acc[2][2] += a2 * b2; acc[2][3] += a2 * b3;
            acc[3][0] += a3 * b0; acc[3][1] += a3 * b1; acc[3][2] += a3 * b2; acc[3][3] += a3 * b3;
        }
        __syncthreads();
    }

#pragma unroll
    for (int i = 0; i < 4; ++i) {
        float4 v = make_float4(acc[i][0], acc[i][1], acc[i][2], acc[i][3]);
        *(float4*)&Cp[((size_t)z * M + by * 64 + ty * 4 + i) * N + bx * 64 + tx * 4] = v;
    }
}

__global__ __launch_bounds__(256) void gemm_f32_splitk(const float* __restrict__ A,
                                                       const float* __restrict__ B,
                                                       float* __restrict__ Cp,
                                                       int M, int N, int K, int KC) {
    __shared__ float As[16][65];
    __shared__ float Bs[16][68];
    gemm_f32_core(A, B, Cp, M, N, K, KC, blockIdx.x, blockIdx.y, blockIdx.z, As, Bs);
}

// ---------------------------------------------------------------------------
// Coalesced split-transpose of one 128(k) x 32(n) tile (round-14 verified).
// ---------------------------------------------------------------------------
__device__ __forceinline__ void transpose_tile(const float* __restrict__ W,
                                               __hip_bfloat16* __restrict__ Th,
                                               __hip_bfloat16* __restrict__ Tl,
                                               int n0, int k0, float Wf[128][33]) {
    const int tid = threadIdx.x;
#pragma unroll
    for (int it = 0; it < 16; ++it) {
        const int idx = it * 256 + tid;
        const int kk  = idx >> 5;
        const int nn  = idx & 31;
        Wf[kk][nn] = W[(size_t)(k0 + kk) * N2 + n0 + nn];
    }
    __syncthreads();

    const int nl  = tid >> 3;
    const int oct = tid & 7;
#pragma unroll
    for (int half = 0; half < 2; ++half) {
        const int kb = half * 64 + oct * 8;
        ushort8 vh, vl;
#pragma unroll
        for (int u = 0; u < 8; ++u) {
            const float w = Wf[kb + u][nl];
            const __hip_bfloat16 hi = __float2bfloat16(w);
            const float lo = w - __bfloat162float(hi);
            const __hip_bfloat16 lb = __float2bfloat16(lo);
            vh[u] = *(const unsigned short*)&hi;
            vl[u] = *(const unsigned short*)&lb;
        }
        const size_t o = (size_t)(n0 + nl) * N1 + k0 + kb;
        *(ushort8*)&Th[o] = vh;
        *(ushort8*)&Tl[o] = vl;
    }
}

__global__ __launch_bounds__(256) void split_transpose_fast(const float* __restrict__ W,
                                                            __hip_bfloat16* __restrict__ Th,
                                                            __hip_bfloat16* __restrict__ Tl) {
    __shared__ float Wf[128][33];
    transpose_tile(W, Th, Tl, blockIdx.x * 32, blockIdx.y * 128, Wf);
}

// ---------------------------------------------------------------------------
// Layer-0 simulate + classify (deterministic per-(b,chunk) residual lists).
// ---------------------------------------------------------------------------
__device__ __forceinline__ void scan_l0_work(const float* __restrict__ P0,
                                             __hip_bfloat16* __restrict__ C0,
                                             int* __restrict__ jlist0,
                                             unsigned long long* __restrict__ mask0,
                                             int* __restrict__ count0,
                                             int b, int chunk, int* wcnt) {
    const int tid  = threadIdx.x;
    const int j    = chunk * 256 + tid;
    const int lane = tid & 63;
    const int wv   = tid >> 6;

    float h = 0.f;
#pragma unroll
    for (int z = 0; z < 8; ++z) h += P0[((size_t)z * BATCH + b) * N1 + j];

    float m = 0.f;
    unsigned long long mask = 0ull;
#pragma unroll
    for (int t = 0; t < TSIM; ++t) {
        m = BETA * m + h;
        if (m - 1.f > 0.f) { mask |= (1ull << t); m = 0.f; }
    }
    const unsigned long long FULL = (1ull << TSIM) - 1ull;
    C0[(size_t)b * N1 + j] = __float2bfloat16((mask == FULL) ? 1.f : 0.f);

    const bool has = (mask != 0ull) && (mask != FULL);
    const unsigned long long bal = __ballot(has);

    if (lane == 0) wcnt[wv] = __popcll(bal);
    __syncthreads();
    int base = 0;
#pragma unroll
    for (int w = 0; w < 4; ++w)
        if (w < wv) base += wcnt[w];
    const int pos = base + __popcll(bal & ((1ull << lane) - 1ull));

    const size_t lbase = (size_t)(b * 8 + chunk) * 256;
    if (has) {
        jlist0[lbase + pos] = j;
        mask0[lbase + pos]  = mask;
    }
    if (tid == 0) count0[b * 8 + chunk] = wcnt[0] + wcnt[1] + wcnt[2] + wcnt[3];
    __syncthreads();   // protect wcnt reuse by later smem users
}

__global__ __launch_bounds__(256) void scan_l0_classify(const float* __restrict__ P0,
                                                        __hip_bfloat16* __restrict__ C0,
                                                        int* __restrict__ jlist0,
                                                        unsigned long long* __restrict__ mask0,
                                                        int* __restrict__ count0) {
    __shared__ int wcnt[4];
    scan_l0_work(P0, C0, jlist0, mask0, count0, blockIdx.x, blockIdx.y, wcnt);
}

// ---------------------------------------------------------------------------
// MFMA GEMM (BN=64, BM=128, BK=32; 4 waves stacked in M; WMT=2, WNT=4):
// Cp[z] = A @ (Bh+Bl)^T. Per-element accumulation order identical to the
// round-14 BN=128 kernel (same K-chunking, hi-then-lo) -> bit-identical.
// ---------------------------------------------------------------------------
__device__ __forceinline__ void gemm_mfma_bn64(const __hip_bfloat16* __restrict__ A,
                                               const __hip_bfloat16* __restrict__ Bh,
                                               const __hip_bfloat16* __restrict__ Bl,
                                               float* __restrict__ Cp,
                                               int bx, int z, int KC,
                                               __hip_bfloat16* As,
                                               __hip_bfloat16* Bhs,
                                               __hip_bfloat16* Bls) {
    constexpr int BM = 128, BN = 64, BK = 32;
    const int M = BATCH, N = N2, K = N1;

    const int tid  = threadIdx.x;
    const int wave = tid >> 6;
    const int lane = tid & 63;
    const int quad = lane >> 4;
    const int l16  = lane & 15;

    const int n0 = bx * BN;
    const int wm = wave * 32;          // WMT=2 tiles of 16 rows per wave

    f32x4 acc[2][4] = {};

    // staging descriptors (A: 2 chunks/thread; B: 1 chunk/thread)
    const __hip_bfloat16* agp[2];
    int aoff[2];
#pragma unroll
    for (int i = 0; i < 2; ++i) {
        const int c = i * 256 + tid;
        agp[i]  = A + (size_t)(c >> 2) * K + (c & 3) * 8;   // m0 = 0 (M == BM)
        aoff[i] = c * 8;
    }
    const __hip_bfloat16* bhgp = Bh + (size_t)(n0 + (tid >> 2)) * K + (tid & 3) * 8;
    const __hip_bfloat16* blgp = Bl + (size_t)(n0 + (tid >> 2)) * K + (tid & 3) * 8;
    const int boff = tid * 8;

    const int kbeg = z * KC;
    for (int k0 = kbeg; k0 < kbeg + KC; k0 += BK) {
#pragma unroll
        for (int i = 0; i < 2; ++i)
            __builtin_amdgcn_global_load_lds((const GLOBAL_AS void*)(agp[i] + k0),
                                             (LDS_AS void*)&As[aoff[i]], 16, 0, 0);
        __builtin_amdgcn_global_load_lds((const GLOBAL_AS void*)(bhgp + k0),
                                         (LDS_AS void*)&Bhs[boff], 16, 0, 0);
        __builtin_amdgcn_global_load_lds((const GLOBAL_AS void*)(blgp + k0),
                                         (LDS_AS void*)&Bls[boff], 16, 0, 0);
        __syncthreads();

        bf16x8 af[2], bhf[4], blf[4];
#pragma unroll
        for (int i = 0; i < 2; ++i)
            af[i] = *(const bf16x8*)&As[(wm + i * 16 + l16) * BK + quad * 8];
#pragma unroll
        for (int j = 0; j < 4; ++j) {
            bhf[j] = *(const bf16x8*)&Bhs[(j * 16 + l16) * BK + quad * 8];
            blf[j] = *(const bf16x8*)&Bls[(j * 16 + l16) * BK + quad * 8];
        }
#pragma unroll
        for (int i = 0; i < 2; ++i)
#pragma unroll
            for (int j = 0; j < 4; ++j) {
                acc[i][j] = __builtin_amdgcn_mfma_f32_16x16x32_bf16(af[i], bhf[j], acc[i][j], 0, 0, 0);
                acc[i][j] = __builtin_amdgcn_mfma_f32_16x16x32_bf16(af[i], blf[j], acc[i][j], 0, 0, 0);
            }
        __syncthreads();
    }

    // C/D layout: col = lane&15, row = quad*4 + reg
#pragma unroll
    for (int i = 0; i < 2; ++i)
#pragma unroll
        for (int j = 0; j < 4; ++j)
#pragma unroll
            for (int r = 0; r < 4; ++r)
                Cp[((size_t)z * M + wm + i * 16 + quad * 4 + r) * N + n0 + j * 16 + l16] =
                    acc[i][j][r];
}

__global__ __launch_bounds__(256) void gemm3_bn64(const __hip_bfloat16* __restrict__ A,
                                                  const __hip_bfloat16* __restrict__ Bh,
                                                  const __hip_bfloat16* __restrict__ Bl,
                                                  float* __restrict__ Cp, int KC) {
    __shared__ alignas(16) __hip_bfloat16 As[128 * 32];
    __shared__ alignas(16) __hip_bfloat16 Bhs[64 * 32];
    __shared__ alignas(16) __hip_bfloat16 Bls[64 * 32];
    gemm_mfma_bn64(A, Bh, Bl, Cp, blockIdx.x, blockIdx.y, KC, As, Bhs, Bls);
}

// ---------------------------------------------------------------------------
// COOPERATIVE front half: transpose + gemm1 -> sync -> scan_l0 -> sync ->
// gemm3. One dispatch instead of 4 (each dispatch gap ~5us). 1024 blocks,
// __launch_bounds__(256,4) -> 4 blocks/CU co-residency. LDS overlaid in one
// 16.9 KB arena (stages separated by grid/block barriers).
// ---------------------------------------------------------------------------
__global__ __launch_bounds__(256, 4) void mega_front(const float* __restrict__ W1,
                                                     __hip_bfloat16* __restrict__ Th,
                                                     __hip_bfloat16* __restrict__ Tl,
                                                     const float* __restrict__ inputs,
                                                     const float* __restrict__ W0,
                                                     float* __restrict__ P0,
                                                     __hip_bfloat16* __restrict__ C0,
                                                     int* __restrict__ jlist0,
                                                     unsigned long long* __restrict__ mask0,
                                                     int* __restrict__ count0,
                                                     float* __restrict__ PB1) {
    __shared__ __align__(16) char smem[16896];   // max(Wf 16896, f32gemm 8512, mfma 16384)
    cg::grid_group grid = cg::this_grid();
    const int bid = blockIdx.x;

    // S0a: W1 split-transpose — one 128x32 tile per block (64 x 16 tiles)
    transpose_tile(W1, Th, Tl, (bid & 63) * 32, (bid >> 6) * 128, (float(*)[33])smem);
    __syncthreads();

    // S0b: gemm1 P0[z] = inputs @ W0 (split-K 8) on blocks [0,512)
    if (bid < 512)
        gemm_f32_core(inputs, W0, P0, BATCH, N1, N0, N0 / 8,
                      bid & 31, (bid >> 5) & 1, bid >> 6,
                      (float(*)[65])smem, (float(*)[68])(smem + 4160));
    grid.sync();

    // S1: scan_l0 — b = bid>>3, chunk = bid&7 (exactly 1024 units)
    scan_l0_work(P0, C0, jlist0, mask0, count0, bid >> 3, bid & 7, (int*)smem);
    grid.sync();

    // S2: gemm3 MFMA BN=64 on blocks [0,512): bx = bid&31, z = bid>>5
    if (bid < 512) {
        __hip_bfloat16* mAs = (__hip_bfloat16*)smem;
        gemm_mfma_bn64(C0, Th, Tl, PB1, bid & 31, bid >> 5, N1 / 16,
                       mAs, mAs + 4096, mAs + 6144);
    }
}

// ---------------------------------------------------------------------------
// Layer-1 fused drive + membrane scan + linear layer-2 projection.
// 50 named scalar accumulators + __launch_bounds__(256,2): the (256,2)
// register budget is what stopped the allocator from spilling (rounds 4-10:
// VGPR 36-68, h1 35-79us; round 11: out of top-5). Do not lower the bound.
// ---------------------------------------------------------------------------
__global__ __launch_bounds__(256, 2) void h1_scan_a2(const float* __restrict__ PB1,
                                                     const float* __restrict__ W1,
                                                     const int* __restrict__ jlist0,
                                                     const unsigned long long* __restrict__ mask0,
                                                     const int* __restrict__ count0,
                                                     float* __restrict__ A2) {
    const int b  = blockIdx.x;
    const int jc = blockIdx.y * 256 + threadIdx.x;

    float base = 0.f;
#pragma unroll
    for (int z = 0; z < 16; ++z) base += PB1[((size_t)z * BATCH + b) * N2 + jc];

    R50(DECLC)

    for (int c = 0; c < 8; ++c) {
        const int cnt      = count0[b * 8 + c];
        const size_t lbase = (size_t)(b * 8 + c) * 256;
        for (int e = 0; e < cnt; ++e) {
            const unsigned long long mk = mask0[lbase + e];
            const int j                 = jlist0[lbase + e];
            const float w               = W1[(size_t)j * N2 + jc];
            const unsigned lo = (unsigned)mk, hi = (unsigned)(mk >> 32);
            R32(PROBELO)
            R18(PROBEHI)
        }
    }

    float s = 0.f, m = 0.f, a2 = 0.f;
    float pa = A50, pb = B50;
    const float inva = 1.0f / ALPHA, invb = 1.0f / BETA;
    R50(STEPT)

    A2[(size_t)b * N2 + jc] = a2;
}

// ---------------------------------------------------------------------------
// Sum 16 split-K partials of A2@W2 -> final output (128 x 512).
// ---------------------------------------------------------------------------
__global__ __launch_bounds__(256) void reduce_out(const float* __restrict__ PB2,
                                                  float* __restrict__ out) {
    const int idx = blockIdx.x * 256 + threadIdx.x;
    float v = 0.f;
#pragma unroll
    for (int z = 0; z < 16; ++z) v += PB2[(size_t)z * (BATCH * N3) + idx];
    out[idx] = v;
}

extern "C" void kernel_launch(void* const* d_in, const int* in_sizes, int n_in,
                              void* d_out, int out_size, void* d_ws, size_t ws_size,
                              hipStream_t stream) {
    const float* inputs = (const float*)d_in[0];   // (128, 1024)
    const float* W0     = (const float*)d_in[1];   // (1024, 2048)
    const float* W1     = (const float*)d_in[2];   // (2048, 2048)
    const float* W2     = (const float*)d_in[3];   // (2048, 512)
    float* out = (float*)d_out;                    // (128, 512)

    // workspace layout (~51 MB) — round-14 structure verbatim
    float* P0  = (float*)d_ws;                         // 8 x 128 x 2048   fp32
    float* PB1 = P0 + 8 * BATCH * N1;                  // 16 x 128 x 2048  fp32
    float* A2  = PB1 + 16 * BATCH * N2;                // 128 x 2048       fp32
    float* PB2 = A2 + BATCH * N2;                      // 16 x 128 x 512   fp32
    unsigned long long* mk0 = (unsigned long long*)(PB2 + 16 * BATCH * N3);  // 128x8x256
    __hip_bfloat16* C0bf = (__hip_bfloat16*)(mk0 + BATCH * 8 * 256);         // 128 x 2048
    __hip_bfloat16* W1th = C0bf + (size_t)BATCH * N1;                        // 2048 x 2048
    __hip_bfloat16* W1tl = W1th + (size_t)N2 * N1;                           // 2048 x 2048
    int* jl0  = (int*)(W1tl + (size_t)N2 * N1);                              // 128 x 8 x 256
    int* cnt0 = jl0 + BATCH * 8 * 256;                                       // 128 x 8

    // Front half: try ONE cooperative dispatch; deterministic fallback to the
    // proven 4-kernel sequence if occupancy/capture can't support it.
    bool coop_ok = false;
    int maxb = 0;
    if (hipOccupancyMaxActiveBlocksPerMultiprocessor(&maxb, (const void*)mega_front,
                                                     256, 0) == hipSuccess &&
        maxb >= 4) {
        void* kargs[] = {(void*)&W1, (void*)&W1th, (void*)&W1tl, (void*)&inputs,
                         (void*)&W0, (void*)&P0, (void*)&C0bf, (void*)&jl0,
                         (void*)&mk0, (void*)&cnt0, (void*)&PB1};
        if (hipLaunchCooperativeKernel((const void*)mega_front, dim3(1024), dim3(256),
                                       kargs, 0, stream) == hipSuccess)
            coop_ok = true;
    }
    if (!coop_ok) {
        split_transpose_fast<<<dim3(N2 / 32, N1 / 128), 256, 0, stream>>>(W1, W1th, W1tl);
        gemm_f32_splitk<<<dim3(N1 / 64, BATCH / 64, 8), 256, 0, stream>>>(
            inputs, W0, P0, BATCH, N1, N0, N0 / 8);
        scan_l0_classify<<<dim3(BATCH, N1 / 256), 256, 0, stream>>>(P0, C0bf, jl0, mk0, cnt0);
        gemm3_bn64<<<dim3(N2 / 64, 16), 256, 0, stream>>>(C0bf, W1th, W1tl, PB1, N1 / 16);
    }

    // Back half (unchanged from round 14)
    h1_scan_a2<<<dim3(BATCH, N2 / 256), 256, 0, stream>>>(
        PB1, W1, jl0, mk0, cnt0, A2);

    gemm_f32_splitk<<<dim3(N3 / 64, BATCH / 64, 16), 256, 0, stream>>>(
        A2, W2, PB2, BATCH, N3, N2, N2 / 16);

    reduce_out<<<(BATCH * N3) / 256, 256, 0, stream>>>(PB2, out);
}